// Round 1
// baseline (1742.127 us; speedup 1.0000x reference)
//
#include <hip/hip_runtime.h>
#include <hip/hip_bf16.h>
#include <cstddef>

// MultiHeadedCrossAttention: fused neighborhood cross-attention.
// Shapes: B=2, I=2048, J=16, NK=2048, D_MODEL=256, D_HIDDEN=512, H=8, D_K=64.
//
// Round 0: correct f32 baseline.
//  K1: qh = q @ Wq            -> ws[0 .. 8MB)    (4096 x 512)
//  K2: kv = k @ Wkv           -> ws[8MB .. 24MB) (4096 x 1024; kk | vv)
//  K3: per-(b,i) fused block:
//      pos tile -> LDS (32KB) -> hidden = relu(pos@W1+b1) -> LDS (32KB)
//      pos_kv = hidden@W2+b2 held in registers (16 j x 4 cols/thread),
//      gather-add kv rows, shfl-butterfly score reduction, per-thread
//      softmax, register V-aggregation -> s_pos reused as agg (2KB),
//      out = agg @ Wout.
//  LDS = exactly 64KB -> 2 blocks/CU (8 waves/CU).
//  All inner-loop LDS reads are wave-uniform (broadcast, no bank conflicts).

#define B_    2
#define I_    2048
#define J_    16
#define NK_   2048
#define DM    256
#define DH    512
#define H_    8
#define DK    64

// ---------------------------------------------------------------------------
// K1/K2: Y[r, c] = sum_k X[r, k] * W[k, c],  X: (rows, 256), W: (256, N).
// 8 rows per block, 256 threads; thread t owns CPT consecutive cols.
// ---------------------------------------------------------------------------
template<int N, int CPT>
__global__ __launch_bounds__(256) void proj_kernel(
    const float* __restrict__ X, const float* __restrict__ W,
    float* __restrict__ Y)
{
  __shared__ float Xs[8 * DM];     // 8 KB
  const int t = threadIdx.x;
  const int row0 = blockIdx.x * 8;

  {
    const float4* x4 = (const float4*)(X + (size_t)row0 * DM);
    float4* s4 = (float4*)Xs;
    s4[t]       = x4[t];
    s4[t + 256] = x4[t + 256];
  }
  __syncthreads();

  float acc[8][CPT];
  #pragma unroll
  for (int r = 0; r < 8; ++r)
    #pragma unroll
    for (int u = 0; u < CPT; ++u) acc[r][u] = 0.f;

  const int c0 = t * CPT;
  for (int k = 0; k < DM; k += 4) {
    float4 xv[8];
    #pragma unroll
    for (int r = 0; r < 8; ++r) xv[r] = *(const float4*)&Xs[r * DM + k];
    #pragma unroll
    for (int kk = 0; kk < 4; ++kk) {
      float w[CPT];
      if constexpr (CPT == 2) {
        const float2 wv = *(const float2*)&W[(size_t)(k + kk) * N + c0];
        w[0] = wv.x; w[1] = wv.y;
      } else {
        const float4 wv = *(const float4*)&W[(size_t)(k + kk) * N + c0];
        w[0] = wv.x; w[1] = wv.y; w[2] = wv.z; w[3] = wv.w;
      }
      #pragma unroll
      for (int r = 0; r < 8; ++r) {
        const float xs = ((const float*)&xv[r])[kk];
        #pragma unroll
        for (int u = 0; u < CPT; ++u) acc[r][u] += xs * w[u];
      }
    }
  }

  #pragma unroll
  for (int r = 0; r < 8; ++r)
    #pragma unroll
    for (int u = 0; u < CPT; ++u)
      Y[(size_t)(row0 + r) * N + c0 + u] = acc[r][u];
}

// ---------------------------------------------------------------------------
// K3: fused pos-MLP + gather + attention + output projection. One block per
// (b, i); 256 threads.
// ---------------------------------------------------------------------------
__global__ __launch_bounds__(256) void fused_attn(
    const float* __restrict__ pos, const int* __restrict__ lidx,
    const float* __restrict__ qh, const float* __restrict__ kv,
    const float* __restrict__ W1, const float* __restrict__ b1,
    const float* __restrict__ W2, const float* __restrict__ b2,
    const float* __restrict__ Wout, float* __restrict__ out)
{
  __shared__ float s_pos[J_ * DH];   // 32 KB; reused as agg[512] at the end
  __shared__ float s_hid[J_ * DH];   // 32 KB

  const int t  = threadIdx.x;
  const int bi = blockIdx.x;         // b*I + i
  const int b  = bi >> 11;           // / 2048

  // local_idx dtype robustness: reference uses int64; harness contract says
  // int32. Detect int64 (little-endian [val,0] pairs) via all-zero odd words
  // of the first 16 elements. Values are in [0,2048) so high words are 0.
  bool idx64;
  {
    int orv = 0;
    #pragma unroll
    for (int m = 0; m < 16; ++m) orv |= lidx[2 * m + 1];
    idx64 = (orv == 0);
  }

  // ---- load pos tile (16 x 512 f32, coalesced float4) ----
  {
    const float4* p4 = (const float4*)(pos + (size_t)bi * (J_ * DH));
    float4* s4 = (float4*)s_pos;
    #pragma unroll
    for (int u = 0; u < 8; ++u) s4[t + u * 256] = p4[t + u * 256];
  }
  __syncthreads();

  // ---- stage 1: hid = relu(pos @ W1 + b1); thread t -> 2 cols, all 16 j ----
  {
    const int c0 = t * 2;
    float acc1[J_][2];
    #pragma unroll
    for (int j = 0; j < J_; ++j) { acc1[j][0] = 0.f; acc1[j][1] = 0.f; }

    for (int k = 0; k < DH; k += 4) {
      float4 pv[J_];
      #pragma unroll
      for (int j = 0; j < J_; ++j) pv[j] = *(const float4*)&s_pos[j * DH + k];
      #pragma unroll
      for (int kk = 0; kk < 4; ++kk) {
        const float2 wv = *(const float2*)&W1[(size_t)(k + kk) * DH + c0];
        #pragma unroll
        for (int j = 0; j < J_; ++j) {
          const float pj = ((const float*)&pv[j])[kk];
          acc1[j][0] += pj * wv.x;
          acc1[j][1] += pj * wv.y;
        }
      }
    }
    const float2 bv = *(const float2*)&b1[c0];
    #pragma unroll
    for (int j = 0; j < J_; ++j) {
      float2 hv;
      hv.x = fmaxf(acc1[j][0] + bv.x, 0.f);
      hv.y = fmaxf(acc1[j][1] + bv.y, 0.f);
      *(float2*)&s_hid[j * DH + c0] = hv;
    }
  }
  __syncthreads();

  // ---- stage 2: pos_kv = hid @ W2 + b2; thread t -> 4 cols of 1024, all j.
  // Column mapping (reference reshape to (H, 2*DK) then split):
  //   c in [0,1024): h = c>>7, cc = c&127; cc<64 -> pos_k[h][cc] (K side,
  //   kv col h*64+cc), else pos_v[h][cc-64] (V side, kv col 512+h*64+cc-64).
  // c0 = t*4 stays within one (h, K/V) region since 4 | 64.
  float acc[J_][4];
  {
    #pragma unroll
    for (int j = 0; j < J_; ++j) {
      acc[j][0] = 0.f; acc[j][1] = 0.f; acc[j][2] = 0.f; acc[j][3] = 0.f;
    }
    const int c0 = t * 4;
    for (int k = 0; k < DH; k += 2) {
      float2 hv[J_];
      #pragma unroll
      for (int j = 0; j < J_; ++j) hv[j] = *(const float2*)&s_hid[j * DH + k];
      #pragma unroll
      for (int kk = 0; kk < 2; ++kk) {
        const float4 wv = *(const float4*)&W2[(size_t)(k + kk) * (2 * DH) + c0];
        #pragma unroll
        for (int j = 0; j < J_; ++j) {
          const float hj = (kk == 0) ? hv[j].x : hv[j].y;
          acc[j][0] += hj * wv.x;
          acc[j][1] += hj * wv.y;
          acc[j][2] += hj * wv.z;
          acc[j][3] += hj * wv.w;
        }
      }
    }
  }

  const int c0v = t * 4;
  const int h   = c0v >> 7;
  const int cc  = c0v & 127;
  const int g0  = h * DK + (cc & 63);   // col in the 512-wide kg/vg space
  const bool isV = (cc >= DK);

  // ---- bias + gather-add: acc becomes kg (K lanes) or vg (V lanes) ----
  {
    const float4 bv = *(const float4*)&b2[c0v];
    #pragma unroll
    for (int j = 0; j < J_; ++j) {
      const int m = bi * J_ + j;
      const int idx = idx64 ? lidx[2 * m] : lidx[m];
      const float* kvrow = kv + ((size_t)b * NK_ + idx) * (2 * DH);
      const float4 gv = *(const float4*)&kvrow[(isV ? DH : 0) + g0];
      acc[j][0] += bv.x + gv.x;
      acc[j][1] += bv.y + gv.y;
      acc[j][2] += bv.z + gv.z;
      acc[j][3] += bv.w + gv.w;
    }
  }

  // ---- scores + softmax ----
  // K lanes for head h=2w: in-wave lanes 0..15; h=2w+1: lanes 32..47.
  // Each K lane holds 4 of the 64 d-columns; butterfly over 16 lanes sums
  // the full dot product, then lane 0/32 broadcasts to the whole half-wave.
  float attnv[J_];
  {
    const float4 q4 = *(const float4*)&qh[(size_t)bi * DH + g0];
    float p[J_];
    #pragma unroll
    for (int j = 0; j < J_; ++j)
      p[j] = q4.x * acc[j][0] + q4.y * acc[j][1] +
             q4.z * acc[j][2] + q4.w * acc[j][3];
    #pragma unroll
    for (int j = 0; j < J_; ++j) {
      p[j] += __shfl_xor(p[j], 1, 64);
      p[j] += __shfl_xor(p[j], 2, 64);
      p[j] += __shfl_xor(p[j], 4, 64);
      p[j] += __shfl_xor(p[j], 8, 64);
      p[j]  = __shfl(p[j], threadIdx.x & 32, 64);  // bcast from K-group head
    }
    float mx = -1e30f;
    #pragma unroll
    for (int j = 0; j < J_; ++j) mx = fmaxf(mx, p[j]);
    float sum = 0.f;
    #pragma unroll
    for (int j = 0; j < J_; ++j) {
      attnv[j] = expf((p[j] - mx) * 0.125f);  // scale = D_K^-0.5 = 1/8
      sum += attnv[j];
    }
    const float inv = 1.f / sum;
    #pragma unroll
    for (int j = 0; j < J_; ++j) attnv[j] *= inv;
  }

  // ---- V aggregation: V lanes hold vg in acc; write agg into s_pos[0..511]
  {
    float a0 = 0.f, a1 = 0.f, a2 = 0.f, a3 = 0.f;
    #pragma unroll
    for (int j = 0; j < J_; ++j) {
      a0 += attnv[j] * acc[j][0];
      a1 += attnv[j] * acc[j][1];
      a2 += attnv[j] * acc[j][2];
      a3 += attnv[j] * acc[j][3];
    }
    if (isV) *(float4*)&s_pos[g0] = make_float4(a0, a1, a2, a3);
  }
  __syncthreads();

  // ---- out[m] = sum_c agg[c] * Wout[c][m]; thread t = column m ----
  {
    float o = 0.f;
    for (int c = 0; c < DH; c += 4) {
      const float4 av = *(const float4*)&s_pos[c];
      o += av.x * Wout[(size_t)(c + 0) * DM + t];
      o += av.y * Wout[(size_t)(c + 1) * DM + t];
      o += av.z * Wout[(size_t)(c + 2) * DM + t];
      o += av.w * Wout[(size_t)(c + 3) * DM + t];
    }
    out[(size_t)bi * DM + t] = o;
  }
}

// ---------------------------------------------------------------------------
extern "C" void kernel_launch(void* const* d_in, const int* in_sizes, int n_in,
                              void* d_out, int out_size, void* d_ws, size_t ws_size,
                              hipStream_t stream)
{
  const float* q    = (const float*)d_in[0];
  const float* k    = (const float*)d_in[1];
  const float* pos  = (const float*)d_in[2];
  const int*   lidx = (const int*)d_in[3];
  const float* Wq   = (const float*)d_in[4];
  const float* Wkv  = (const float*)d_in[5];
  const float* W1   = (const float*)d_in[6];
  const float* b1   = (const float*)d_in[7];
  const float* W2   = (const float*)d_in[8];
  const float* b2   = (const float*)d_in[9];
  const float* Wout = (const float*)d_in[10];
  float* out = (float*)d_out;

  // workspace: qh (4096x512 f32 = 8MB) | kv (4096x1024 f32 = 16MB)
  float* qh_ws = (float*)d_ws;
  float* kv_ws = qh_ws + (size_t)(B_ * I_) * DH;

  proj_kernel<DH, 2>     <<<(B_ * I_)  / 8, 256, 0, stream>>>(q, Wq,  qh_ws);
  proj_kernel<2 * DH, 4> <<<(B_ * NK_) / 8, 256, 0, stream>>>(k, Wkv, kv_ws);
  fused_attn<<<B_ * I_, 256, 0, stream>>>(pos, lidx, qh_ws, kv_ws,
                                          W1, b1, W2, b2, Wout, out);
}

// Round 2
// 496.957 us; speedup vs baseline: 3.5056x; 3.5056x over previous
//
#include <hip/hip_runtime.h>
#include <hip/hip_bf16.h>
#include <cstddef>

// MultiHeadedCrossAttention, Round 2: bf16-MFMA pos-MLP, f32 everything else.
// B=2, I=2048, J=16, NK=2048, D_MODEL=256, D_HIDDEN=512, H=8, D_K=64.
//
//  K_sw1/K_sw2: pre-swizzle W1/W2 -> bf16 B-fragment order in ws (1.5 MB, L2-hot)
//  K1: qh = q @ Wq  (f32, unchanged)
//  K2: kv = k @ Wkv (f32, unchanged)
//  K3 fused_mfma: one block per 4 i's (M=64 rows = 4 MFMA m-tiles; m-tile == i,
//     rows == j). pos -> LDS in A-frag order (bf16). Stage1 MFMA (K=512) ->
//     relu+b1 -> scatter back to LDS in stage2 A-frag order. Stage2: one head
//     per wave-pass (2 passes), epilogue in MFMA C-layout: gather-add kv (f32),
//     shfl-xor score reduce, softmax, register V-agg. Then agg -> LDS overlay,
//     f32 out-projection with wave-split-K partials.
//  LDS = exactly 64KB -> 2 blocks/CU.

#define B_  2
#define I_  2048
#define J_  16
#define NK_ 2048
#define DM  256
#define DH  512
#define H_  8
#define DK  64
#define G_  4    // i's per fused block

typedef __attribute__((ext_vector_type(8))) __bf16 bf16x8;
typedef __attribute__((ext_vector_type(4))) float f32x4;
typedef __attribute__((ext_vector_type(8))) unsigned short ushort8;

__device__ inline unsigned short f2bf(float f) {   // RNE float->bf16
  unsigned int u = __builtin_bit_cast(unsigned int, f);
  u += 0x7FFFu + ((u >> 16) & 1u);
  return (unsigned short)(u >> 16);
}

// ---------------------------------------------------------------------------
// Weight pre-swizzle: W (K=512 rows, N cols, f32 row-major) -> bf16 B-frags.
// Frag (nt, ks): lane l holds B[k = ks*32 + (l>>4)*8 + j][n = nt*16 + (l&15)],
// j=0..7, stored 16B-contiguous at Wf[((nt*16+ks)*64 + l)*8].
// ---------------------------------------------------------------------------
template<int N>
__global__ __launch_bounds__(256) void swizzle_w(
    const float* __restrict__ W, unsigned short* __restrict__ Wf)
{
  const int u  = blockIdx.x * 256 + threadIdx.x;   // (N/16)*16*64 threads
  const int l  = u & 63;
  const int fi = u >> 6;           // nt*16 + ks
  const int ks = fi & 15;
  const int nt = fi >> 4;
  const int n  = nt * 16 + (l & 15);
  const int k0 = ks * 32 + (l >> 4) * 8;
  unsigned short tmp[8];
  #pragma unroll
  for (int j = 0; j < 8; ++j) tmp[j] = f2bf(W[(size_t)(k0 + j) * N + n]);
  *(ushort8*)&Wf[(size_t)u * 8] = *(const ushort8*)tmp;
}

// ---------------------------------------------------------------------------
// K1/K2: Y = X @ W, X: (rows, 256) f32. 8 rows/block, 256 threads.
// ---------------------------------------------------------------------------
template<int N, int CPT>
__global__ __launch_bounds__(256) void proj_kernel(
    const float* __restrict__ X, const float* __restrict__ W,
    float* __restrict__ Y)
{
  __shared__ float Xs[8 * DM];
  const int t = threadIdx.x;
  const int row0 = blockIdx.x * 8;
  {
    const float4* x4 = (const float4*)(X + (size_t)row0 * DM);
    float4* s4 = (float4*)Xs;
    s4[t] = x4[t]; s4[t + 256] = x4[t + 256];
  }
  __syncthreads();

  float acc[8][CPT];
  #pragma unroll
  for (int r = 0; r < 8; ++r)
    #pragma unroll
    for (int u = 0; u < CPT; ++u) acc[r][u] = 0.f;

  const int c0 = t * CPT;
  for (int k = 0; k < DM; k += 4) {
    float4 xv[8];
    #pragma unroll
    for (int r = 0; r < 8; ++r) xv[r] = *(const float4*)&Xs[r * DM + k];
    #pragma unroll
    for (int kk = 0; kk < 4; ++kk) {
      float w[CPT];
      if constexpr (CPT == 2) {
        const float2 wv = *(const float2*)&W[(size_t)(k + kk) * N + c0];
        w[0] = wv.x; w[1] = wv.y;
      } else {
        const float4 wv = *(const float4*)&W[(size_t)(k + kk) * N + c0];
        w[0] = wv.x; w[1] = wv.y; w[2] = wv.z; w[3] = wv.w;
      }
      #pragma unroll
      for (int r = 0; r < 8; ++r) {
        const float xs = ((const float*)&xv[r])[kk];
        #pragma unroll
        for (int u = 0; u < CPT; ++u) acc[r][u] += xs * w[u];
      }
    }
  }
  #pragma unroll
  for (int r = 0; r < 8; ++r)
    #pragma unroll
    for (int u = 0; u < CPT; ++u)
      Y[(size_t)(row0 + r) * N + c0 + u] = acc[r][u];
}

// ---------------------------------------------------------------------------
// K3: fused MFMA pos-MLP + gather + attention + out-projection.
// ---------------------------------------------------------------------------
__global__ __launch_bounds__(256, 2) void fused_mfma(
    const float* __restrict__ pos, const int* __restrict__ lidx,
    const float* __restrict__ qh, const float* __restrict__ kv,
    const unsigned short* __restrict__ W1f, const float* __restrict__ b1,
    const unsigned short* __restrict__ W2f, const float* __restrict__ b2,
    const float* __restrict__ Wout, float* __restrict__ out)
{
  __shared__ unsigned short s_a[G_ * 16 * 64 * 8];   // 64 KB, multi-purpose

  const int t    = threadIdx.x;
  const int lane = t & 63;
  const int w    = t >> 6;        // wave 0..3
  const int g    = lane >> 4;     // row-group within C layout
  const int c16  = lane & 15;     // col within 16-tile
  const int bi0  = blockIdx.x * G_;
  const int b    = bi0 >> 11;     // / I_

  // local_idx may be int64 (reference) or int32; detect (values < 2048 so
  // int64 high words are all zero).
  bool idx64;
  {
    int orv = 0;
    #pragma unroll
    for (int m = 0; m < 16; ++m) orv |= lidx[2 * m + 1];
    idx64 = (orv == 0);
  }
  // gather indices this lane needs: j = g*4 + r for each i (=m-tile)
  int idxr[G_][4];
  #pragma unroll
  for (int mt = 0; mt < G_; ++mt)
    #pragma unroll
    for (int r = 0; r < 4; ++r) {
      const int e = (bi0 + mt) * J_ + g * 4 + r;
      idxr[mt][r] = idx64 ? lidx[2 * e] : lidx[e];
    }

  // ---- stage pos (64 rows x 512 cols) -> s_a in A-frag order (bf16) ----
  // u = fi*64 + lane_d; fi = mt*16 + ks; lane_d holds (m = lane_d&15,
  // kgroup = lane_d>>4): element (row = mt*16+m, col = ks*32 + kgroup*8 + j).
  #pragma unroll
  for (int it = 0; it < 16; ++it) {
    const int u  = t + it * 256;
    const int fi = u >> 6, ld = u & 63;
    const int mt = fi >> 4, ks = fi & 15;
    const int row = mt * 16 + (ld & 15);
    const int col = ks * 32 + (ld >> 4) * 8;
    const float* src = pos + (size_t)(bi0 * J_ + row) * DH + col;
    const float4 v0 = *(const float4*)src;
    const float4 v1 = *(const float4*)(src + 4);
    unsigned short tmp[8];
    tmp[0] = f2bf(v0.x); tmp[1] = f2bf(v0.y); tmp[2] = f2bf(v0.z); tmp[3] = f2bf(v0.w);
    tmp[4] = f2bf(v1.x); tmp[5] = f2bf(v1.y); tmp[6] = f2bf(v1.z); tmp[7] = f2bf(v1.w);
    *(ushort8*)&s_a[(size_t)u * 8] = *(const ushort8*)tmp;
  }
  __syncthreads();

  const f32x4 zero4 = {0.f, 0.f, 0.f, 0.f};

  // ---- stage 1: hidden = relu(pos @ W1 + b1); wave w owns cols w*128.. ----
  f32x4 acc1[G_][8];
  #pragma unroll
  for (int mt = 0; mt < G_; ++mt)
    #pragma unroll
    for (int nt = 0; nt < 8; ++nt) acc1[mt][nt] = zero4;

  for (int ks = 0; ks < 16; ++ks) {
    bf16x8 a[G_];
    #pragma unroll
    for (int mt = 0; mt < G_; ++mt)
      a[mt] = *(const bf16x8*)&s_a[((mt * 16 + ks) * 64 + lane) * 8];
    #pragma unroll
    for (int nt = 0; nt < 8; ++nt) {
      const int ntg = w * 8 + nt;
      const bf16x8 bf = *(const bf16x8*)&W1f[((size_t)(ntg * 16 + ks) * 64 + lane) * 8];
      #pragma unroll
      for (int mt = 0; mt < G_; ++mt)
        acc1[mt][nt] = __builtin_amdgcn_mfma_f32_16x16x32_bf16(a[mt], bf, acc1[mt][nt], 0, 0, 0);
    }
  }
  __syncthreads();   // everyone done reading pos frags

  // ---- relu + b1, scatter into s_a as stage-2 A-frags (element (m, k=col)):
  // frag fi = mt*16 + (col>>5), lane = (m&15) + ((col>>3)&3)*16, byte = col&7
  #pragma unroll
  for (int nt = 0; nt < 8; ++nt) {
    const int col  = (w * 8 + nt) * 16 + c16;
    const float bb = b1[col];
    const int ks2  = col >> 5;
    const int lsel = ((col >> 3) & 3) * 16;
    const int bj   = col & 7;
    #pragma unroll
    for (int mt = 0; mt < G_; ++mt)
      #pragma unroll
      for (int r = 0; r < 4; ++r) {
        const float hv = fmaxf(acc1[mt][nt][r] + bb, 0.f);
        s_a[((mt * 16 + ks2) * 64 + (g * 4 + r) + lsel) * 8 + bj] = f2bf(hv);
      }
  }
  __syncthreads();

  // ---- stage 2 + attention: one head per pass; wave w -> heads 2w, 2w+1 ----
  float agg[2][G_][4];   // [pass][i][d-tile] : this lane's agg cols
  #pragma unroll
  for (int p = 0; p < 2; ++p) {
    const int h = 2 * w + p;
    f32x4 acc2[G_][8];   // tt 0..3 = K-side (d = tt*16+c16), 4..7 = V-side
    #pragma unroll
    for (int mt = 0; mt < G_; ++mt)
      #pragma unroll
      for (int tt = 0; tt < 8; ++tt) acc2[mt][tt] = zero4;

    for (int ks = 0; ks < 16; ++ks) {
      bf16x8 a[G_];
      #pragma unroll
      for (int mt = 0; mt < G_; ++mt)
        a[mt] = *(const bf16x8*)&s_a[((mt * 16 + ks) * 64 + lane) * 8];
      #pragma unroll
      for (int tt = 0; tt < 8; ++tt) {
        const int ntg = h * 8 + tt;   // pos_kv cols h*128 + tt*16 ..
        const bf16x8 bf = *(const bf16x8*)&W2f[((size_t)(ntg * 16 + ks) * 64 + lane) * 8];
        #pragma unroll
        for (int mt = 0; mt < G_; ++mt)
          acc2[mt][tt] = __builtin_amdgcn_mfma_f32_16x16x32_bf16(a[mt], bf, acc2[mt][tt], 0, 0, 0);
      }
    }

    // epilogue for head h (all f32). C layout: col = c16, row m = g*4 + reg.
    float b2k[4], b2v[4], qv[G_][4];
    #pragma unroll
    for (int tt = 0; tt < 4; ++tt) {
      b2k[tt] = b2[h * 128 + tt * 16 + c16];
      b2v[tt] = b2[h * 128 + 64 + tt * 16 + c16];
    }
    #pragma unroll
    for (int mt = 0; mt < G_; ++mt)
      #pragma unroll
      for (int tt = 0; tt < 4; ++tt)
        qv[mt][tt] = qh[(size_t)(bi0 + mt) * DH + h * 64 + tt * 16 + c16];

    #pragma unroll
    for (int mt = 0; mt < G_; ++mt) {
      float pj[4];
      #pragma unroll
      for (int r = 0; r < 4; ++r) {
        const float* kvrow = kv + ((size_t)b * NK_ + idxr[mt][r]) * (2 * DH);
        float s = 0.f;
        #pragma unroll
        for (int tt = 0; tt < 4; ++tt) {
          const int d = h * 64 + tt * 16 + c16;
          const float kg = acc2[mt][tt][r] + b2k[tt] + kvrow[d];
          s += qv[mt][tt] * kg;
          acc2[mt][4 + tt][r] += b2v[tt] + kvrow[DH + d];   // vg in place
        }
        s += __shfl_xor(s, 1);  s += __shfl_xor(s, 2);
        s += __shfl_xor(s, 4);  s += __shfl_xor(s, 8);      // full q.kg
        pj[r] = s * 0.125f;                                  // D_K^-0.5
      }
      // softmax over the 16 j (j = g*4 + r): cross-group via xor 16/32
      float mx = fmaxf(fmaxf(pj[0], pj[1]), fmaxf(pj[2], pj[3]));
      mx = fmaxf(mx, __shfl_xor(mx, 16));
      mx = fmaxf(mx, __shfl_xor(mx, 32));
      float sum = 0.f;
      #pragma unroll
      for (int r = 0; r < 4; ++r) { pj[r] = __expf(pj[r] - mx); sum += pj[r]; }
      sum += __shfl_xor(sum, 16);
      sum += __shfl_xor(sum, 32);
      const float inv = 1.f / sum;
      #pragma unroll
      for (int r = 0; r < 4; ++r) pj[r] *= inv;
      // V aggregation; xor 16/32 sums over all j groups
      #pragma unroll
      for (int tt = 0; tt < 4; ++tt) {
        float a_ = pj[0] * acc2[mt][4 + tt][0] + pj[1] * acc2[mt][4 + tt][1]
                 + pj[2] * acc2[mt][4 + tt][2] + pj[3] * acc2[mt][4 + tt][3];
        a_ += __shfl_xor(a_, 16);
        a_ += __shfl_xor(a_, 32);
        agg[p][mt][tt] = a_;
      }
    }
  }
  __syncthreads();   // all waves done reading s_a (hidden frags)

  // ---- write agg into s_a overlay: s_agg[i][512] f32 (8 KB) ----
  float* s_agg = (float*)s_a;
  if (g == 0) {
    #pragma unroll
    for (int p = 0; p < 2; ++p) {
      const int h = 2 * w + p;
      #pragma unroll
      for (int mt = 0; mt < G_; ++mt)
        #pragma unroll
        for (int tt = 0; tt < 4; ++tt)
          s_agg[mt * DH + h * 64 + tt * 16 + c16] = agg[p][mt][tt];
    }
  }
  __syncthreads();

  // ---- out = agg @ Wout; wave w sums k-range [w*128, w*128+128) ----
  float* s_part = (float*)s_a + G_ * DH;   // bytes [8KB, 24KB)
  f32x4 oacc[G_];
  #pragma unroll
  for (int i = 0; i < G_; ++i) oacc[i] = zero4;
  for (int c4 = 0; c4 < 32; ++c4) {
    const int c = w * 128 + c4 * 4;
    f32x4 ag[G_];
    #pragma unroll
    for (int i = 0; i < G_; ++i) ag[i] = *(const f32x4*)&s_agg[i * DH + c];
    #pragma unroll
    for (int cc = 0; cc < 4; ++cc) {
      const f32x4 wv = *(const f32x4*)&Wout[(size_t)(c + cc) * DM + lane * 4];
      #pragma unroll
      for (int i = 0; i < G_; ++i) oacc[i] += wv * ag[i][cc];
    }
  }
  #pragma unroll
  for (int i = 0; i < G_; ++i)
    *(f32x4*)&s_part[(w * G_ + i) * DM + lane * 4] = oacc[i];
  __syncthreads();

  #pragma unroll
  for (int i = 0; i < G_; ++i) {
    const float o = s_part[(0 * G_ + i) * DM + t] + s_part[(1 * G_ + i) * DM + t]
                  + s_part[(2 * G_ + i) * DM + t] + s_part[(3 * G_ + i) * DM + t];
    out[(size_t)(bi0 + i) * DM + t] = o;
  }
}

// ---------------------------------------------------------------------------
extern "C" void kernel_launch(void* const* d_in, const int* in_sizes, int n_in,
                              void* d_out, int out_size, void* d_ws, size_t ws_size,
                              hipStream_t stream)
{
  const float* q    = (const float*)d_in[0];
  const float* k    = (const float*)d_in[1];
  const float* pos  = (const float*)d_in[2];
  const int*   lidx = (const int*)d_in[3];
  const float* Wq   = (const float*)d_in[4];
  const float* Wkv  = (const float*)d_in[5];
  const float* W1   = (const float*)d_in[6];
  const float* b1   = (const float*)d_in[7];
  const float* W2   = (const float*)d_in[8];
  const float* b2   = (const float*)d_in[9];
  const float* Wout = (const float*)d_in[10];
  float* out = (float*)d_out;

  // ws: qh 8MB | kv 16MB | W1f 512KB | W2f 1MB
  float* qh_ws = (float*)d_ws;
  float* kv_ws = qh_ws + (size_t)(B_ * I_) * DH;
  unsigned short* W1f = (unsigned short*)(kv_ws + (size_t)(B_ * NK_) * (2 * DH));
  unsigned short* W2f = W1f + (size_t)DH * DH;

  swizzle_w<DH>     <<<(DH / 16) * 16 * 64 / 256, 256, 0, stream>>>(W1, W1f);
  swizzle_w<2 * DH> <<<(2 * DH / 16) * 16 * 64 / 256, 256, 0, stream>>>(W2, W2f);
  proj_kernel<DH, 2>     <<<(B_ * I_)  / 8, 256, 0, stream>>>(q, Wq,  qh_ws);
  proj_kernel<2 * DH, 4> <<<(B_ * NK_) / 8, 256, 0, stream>>>(k, Wkv, kv_ws);
  fused_mfma<<<(B_ * I_) / G_, 256, 0, stream>>>(pos, lidx, qh_ws, kv_ws,
                                                 W1f, b1, W2f, b2, Wout, out);
}

// Round 4
// 460.522 us; speedup vs baseline: 3.7829x; 1.0791x over previous
//
#include <hip/hip_runtime.h>
#include <hip/hip_bf16.h>
#include <cstddef>

// MultiHeadedCrossAttention, Round 4 (bisect round).
// B=2, I=2048, J=16, NK=2048, D_MODEL=256, D_HIDDEN=512, H=8, D_K=64.
//
// R3 (merged pre + LDS-free proj + fused weight prefetch) failed absmax
// 1.75e-2 with no identifiable semantic diff from R2 -> bisect. R4 keeps
// R2's fused_mfma VERBATIM and R2's LDS-staged proj/swizzle bodies VERBATIM,
// changing only the dispatch: all pre-work in ONE 1408-block kernel
// (block-uniform branch; per-branch __syncthreads is block-uniform -> legal).
//  blocks [0,512):    qh = q @ Wq      (8 rows/block, LDS-staged X)
//  blocks [512,1024): kv = k @ Wkv
//  blocks [1024,1152): W1 -> bf16 B-frag swizzle
//  blocks [1152,1408): W2 -> bf16 B-frag swizzle

#define B_  2
#define I_  2048
#define J_  16
#define NK_ 2048
#define DM  256
#define DH  512
#define H_  8
#define DK  64
#define G_  4    // i's per fused block

typedef __attribute__((ext_vector_type(8))) __bf16 bf16x8;
typedef __attribute__((ext_vector_type(4))) float f32x4;
typedef __attribute__((ext_vector_type(8))) unsigned short ushort8;

__device__ inline unsigned short f2bf(float f) {   // RNE float->bf16
  unsigned int u = __builtin_bit_cast(unsigned int, f);
  u += 0x7FFFu + ((u >> 16) & 1u);
  return (unsigned short)(u >> 16);
}

// ---------------------------------------------------------------------------
// Pre-kernel bodies (R2-verbatim math)
// ---------------------------------------------------------------------------

// Weight pre-swizzle: W (512 x N f32 row-major) -> bf16 B-frags.
// Frag (nt, ks): lane l holds B[k = ks*32 + (l>>4)*8 + j][n = nt*16 + (l&15)],
// j=0..7, 16B-contiguous at Wf[((nt*16+ks)*64 + l)*8].
template<int N>
__device__ void swz_body(const float* __restrict__ W,
                         unsigned short* __restrict__ Wf, int bid, int t)
{
  const int u  = bid * 256 + t;
  const int l  = u & 63;
  const int fi = u >> 6;
  const int ks = fi & 15;
  const int nt = fi >> 4;
  const int n  = nt * 16 + (l & 15);
  const int k0 = ks * 32 + (l >> 4) * 8;
  unsigned short tmp[8];
  #pragma unroll
  for (int j = 0; j < 8; ++j) tmp[j] = f2bf(W[(size_t)(k0 + j) * N + n]);
  *(ushort8*)&Wf[(size_t)u * 8] = *(const ushort8*)tmp;
}

// Y = X @ W, X: (rows, 256) f32, LDS-staged X (R2-verbatim).
template<int N, int CPT>
__device__ void proj_body(const float* __restrict__ X,
                          const float* __restrict__ W,
                          float* __restrict__ Y, float* Xs, int bid, int t)
{
  const int row0 = bid * 8;
  {
    const float4* x4 = (const float4*)(X + (size_t)row0 * DM);
    float4* s4 = (float4*)Xs;
    s4[t] = x4[t]; s4[t + 256] = x4[t + 256];
  }
  __syncthreads();

  float acc[8][CPT];
  #pragma unroll
  for (int r = 0; r < 8; ++r)
    #pragma unroll
    for (int u = 0; u < CPT; ++u) acc[r][u] = 0.f;

  const int c0 = t * CPT;
  for (int k = 0; k < DM; k += 4) {
    float4 xv[8];
    #pragma unroll
    for (int r = 0; r < 8; ++r) xv[r] = *(const float4*)&Xs[r * DM + k];
    #pragma unroll
    for (int kk = 0; kk < 4; ++kk) {
      float w[CPT];
      if constexpr (CPT == 2) {
        const float2 wv = *(const float2*)&W[(size_t)(k + kk) * N + c0];
        w[0] = wv.x; w[1] = wv.y;
      } else {
        const float4 wv = *(const float4*)&W[(size_t)(k + kk) * N + c0];
        w[0] = wv.x; w[1] = wv.y; w[2] = wv.z; w[3] = wv.w;
      }
      #pragma unroll
      for (int r = 0; r < 8; ++r) {
        const float xs = ((const float*)&xv[r])[kk];
        #pragma unroll
        for (int u = 0; u < CPT; ++u) acc[r][u] += xs * w[u];
      }
    }
  }
  #pragma unroll
  for (int r = 0; r < 8; ++r)
    #pragma unroll
    for (int u = 0; u < CPT; ++u)
      Y[(size_t)(row0 + r) * N + c0 + u] = acc[r][u];
}

// Merged pre-kernel. Branch is block-uniform.
__global__ __launch_bounds__(256) void pre_kernel(
    const float* __restrict__ q, const float* __restrict__ k,
    const float* __restrict__ Wq, const float* __restrict__ Wkv,
    const float* __restrict__ W1, const float* __restrict__ W2,
    float* __restrict__ qh_ws, float* __restrict__ kv_ws,
    unsigned short* __restrict__ W1f, unsigned short* __restrict__ W2f)
{
  __shared__ float Xs[8 * DM];
  const int bid = blockIdx.x;
  const int t = threadIdx.x;
  if (bid < 512)        proj_body<DH, 2>   (q, Wq,  qh_ws, Xs, bid, t);
  else if (bid < 1024)  proj_body<2*DH, 4> (k, Wkv, kv_ws, Xs, bid - 512, t);
  else if (bid < 1152)  swz_body<DH>       (W1, W1f, bid - 1024, t);
  else                  swz_body<2*DH>     (W2, W2f, bid - 1152, t);
}

// ---------------------------------------------------------------------------
// K3: fused MFMA pos-MLP + gather + attention + out-projection (R2 VERBATIM).
// ---------------------------------------------------------------------------
__global__ __launch_bounds__(256, 2) void fused_mfma(
    const float* __restrict__ pos, const int* __restrict__ lidx,
    const float* __restrict__ qh, const float* __restrict__ kv,
    const unsigned short* __restrict__ W1f, const float* __restrict__ b1,
    const unsigned short* __restrict__ W2f, const float* __restrict__ b2,
    const float* __restrict__ Wout, float* __restrict__ out)
{
  __shared__ unsigned short s_a[G_ * 16 * 64 * 8];   // 64 KB, multi-purpose

  const int t    = threadIdx.x;
  const int lane = t & 63;
  const int w    = t >> 6;        // wave 0..3
  const int g    = lane >> 4;     // row-group within C layout
  const int c16  = lane & 15;     // col within 16-tile
  const int bi0  = blockIdx.x * G_;
  const int b    = bi0 >> 11;     // / I_

  // local_idx may be int64 (reference) or int32; detect (values < 2048 so
  // int64 high words are all zero).
  bool idx64;
  {
    int orv = 0;
    #pragma unroll
    for (int m = 0; m < 16; ++m) orv |= lidx[2 * m + 1];
    idx64 = (orv == 0);
  }
  // gather indices this lane needs: j = g*4 + r for each i (=m-tile)
  int idxr[G_][4];
  #pragma unroll
  for (int mt = 0; mt < G_; ++mt)
    #pragma unroll
    for (int r = 0; r < 4; ++r) {
      const int e = (bi0 + mt) * J_ + g * 4 + r;
      idxr[mt][r] = idx64 ? lidx[2 * e] : lidx[e];
    }

  // ---- stage pos (64 rows x 512 cols) -> s_a in A-frag order (bf16) ----
  #pragma unroll
  for (int it = 0; it < 16; ++it) {
    const int u  = t + it * 256;
    const int fi = u >> 6, ld = u & 63;
    const int mt = fi >> 4, ks = fi & 15;
    const int row = mt * 16 + (ld & 15);
    const int col = ks * 32 + (ld >> 4) * 8;
    const float* src = pos + (size_t)(bi0 * J_ + row) * DH + col;
    const float4 v0 = *(const float4*)src;
    const float4 v1 = *(const float4*)(src + 4);
    unsigned short tmp[8];
    tmp[0] = f2bf(v0.x); tmp[1] = f2bf(v0.y); tmp[2] = f2bf(v0.z); tmp[3] = f2bf(v0.w);
    tmp[4] = f2bf(v1.x); tmp[5] = f2bf(v1.y); tmp[6] = f2bf(v1.z); tmp[7] = f2bf(v1.w);
    *(ushort8*)&s_a[(size_t)u * 8] = *(const ushort8*)tmp;
  }
  __syncthreads();

  const f32x4 zero4 = {0.f, 0.f, 0.f, 0.f};

  // ---- stage 1: hidden = relu(pos @ W1 + b1); wave w owns cols w*128.. ----
  f32x4 acc1[G_][8];
  #pragma unroll
  for (int mt = 0; mt < G_; ++mt)
    #pragma unroll
    for (int nt = 0; nt < 8; ++nt) acc1[mt][nt] = zero4;

  for (int ks = 0; ks < 16; ++ks) {
    bf16x8 a[G_];
    #pragma unroll
    for (int mt = 0; mt < G_; ++mt)
      a[mt] = *(const bf16x8*)&s_a[((mt * 16 + ks) * 64 + lane) * 8];
    #pragma unroll
    for (int nt = 0; nt < 8; ++nt) {
      const int ntg = w * 8 + nt;
      const bf16x8 bf = *(const bf16x8*)&W1f[((size_t)(ntg * 16 + ks) * 64 + lane) * 8];
      #pragma unroll
      for (int mt = 0; mt < G_; ++mt)
        acc1[mt][nt] = __builtin_amdgcn_mfma_f32_16x16x32_bf16(a[mt], bf, acc1[mt][nt], 0, 0, 0);
    }
  }
  __syncthreads();   // everyone done reading pos frags

  // ---- relu + b1, scatter into s_a as stage-2 A-frags ----
  #pragma unroll
  for (int nt = 0; nt < 8; ++nt) {
    const int col  = (w * 8 + nt) * 16 + c16;
    const float bb = b1[col];
    const int ks2  = col >> 5;
    const int lsel = ((col >> 3) & 3) * 16;
    const int bj   = col & 7;
    #pragma unroll
    for (int mt = 0; mt < G_; ++mt)
      #pragma unroll
      for (int r = 0; r < 4; ++r) {
        const float hv = fmaxf(acc1[mt][nt][r] + bb, 0.f);
        s_a[((mt * 16 + ks2) * 64 + (g * 4 + r) + lsel) * 8 + bj] = f2bf(hv);
      }
  }
  __syncthreads();

  // ---- stage 2 + attention: one head per pass; wave w -> heads 2w, 2w+1 ----
  float agg[2][G_][4];   // [pass][i][d-tile]
  #pragma unroll
  for (int p = 0; p < 2; ++p) {
    const int h = 2 * w + p;
    f32x4 acc2[G_][8];   // tt 0..3 = K-side (d = tt*16+c16), 4..7 = V-side
    #pragma unroll
    for (int mt = 0; mt < G_; ++mt)
      #pragma unroll
      for (int tt = 0; tt < 8; ++tt) acc2[mt][tt] = zero4;

    for (int ks = 0; ks < 16; ++ks) {
      bf16x8 a[G_];
      #pragma unroll
      for (int mt = 0; mt < G_; ++mt)
        a[mt] = *(const bf16x8*)&s_a[((mt * 16 + ks) * 64 + lane) * 8];
      #pragma unroll
      for (int tt = 0; tt < 8; ++tt) {
        const int ntg = h * 8 + tt;   // pos_kv cols h*128 + tt*16 ..
        const bf16x8 bf = *(const bf16x8*)&W2f[((size_t)(ntg * 16 + ks) * 64 + lane) * 8];
        #pragma unroll
        for (int mt = 0; mt < G_; ++mt)
          acc2[mt][tt] = __builtin_amdgcn_mfma_f32_16x16x32_bf16(a[mt], bf, acc2[mt][tt], 0, 0, 0);
      }
    }

    // epilogue for head h (all f32). C layout: col = c16, row m = g*4 + reg.
    float b2k[4], b2v[4], qv[G_][4];
    #pragma unroll
    for (int tt = 0; tt < 4; ++tt) {
      b2k[tt] = b2[h * 128 + tt * 16 + c16];
      b2v[tt] = b2[h * 128 + 64 + tt * 16 + c16];
    }
    #pragma unroll
    for (int mt = 0; mt < G_; ++mt)
      #pragma unroll
      for (int tt = 0; tt < 4; ++tt)
        qv[mt][tt] = qh[(size_t)(bi0 + mt) * DH + h * 64 + tt * 16 + c16];

    #pragma unroll
    for (int mt = 0; mt < G_; ++mt) {
      float pj[4];
      #pragma unroll
      for (int r = 0; r < 4; ++r) {
        const float* kvrow = kv + ((size_t)b * NK_ + idxr[mt][r]) * (2 * DH);
        float s = 0.f;
        #pragma unroll
        for (int tt = 0; tt < 4; ++tt) {
          const int d = h * 64 + tt * 16 + c16;
          const float kg = acc2[mt][tt][r] + b2k[tt] + kvrow[d];
          s += qv[mt][tt] * kg;
          acc2[mt][4 + tt][r] += b2v[tt] + kvrow[DH + d];   // vg in place
        }
        s += __shfl_xor(s, 1);  s += __shfl_xor(s, 2);
        s += __shfl_xor(s, 4);  s += __shfl_xor(s, 8);      // full q.kg
        pj[r] = s * 0.125f;                                  // D_K^-0.5
      }
      // softmax over the 16 j (j = g*4 + r): cross-group via xor 16/32
      float mx = fmaxf(fmaxf(pj[0], pj[1]), fmaxf(pj[2], pj[3]));
      mx = fmaxf(mx, __shfl_xor(mx, 16));
      mx = fmaxf(mx, __shfl_xor(mx, 32));
      float sum = 0.f;
      #pragma unroll
      for (int r = 0; r < 4; ++r) { pj[r] = __expf(pj[r] - mx); sum += pj[r]; }
      sum += __shfl_xor(sum, 16);
      sum += __shfl_xor(sum, 32);
      const float inv = 1.f / sum;
      #pragma unroll
      for (int r = 0; r < 4; ++r) pj[r] *= inv;
      // V aggregation; xor 16/32 sums over all j groups
      #pragma unroll
      for (int tt = 0; tt < 4; ++tt) {
        float a_ = pj[0] * acc2[mt][4 + tt][0] + pj[1] * acc2[mt][4 + tt][1]
                 + pj[2] * acc2[mt][4 + tt][2] + pj[3] * acc2[mt][4 + tt][3];
        a_ += __shfl_xor(a_, 16);
        a_ += __shfl_xor(a_, 32);
        agg[p][mt][tt] = a_;
      }
    }
  }
  __syncthreads();   // all waves done reading s_a (hidden frags)

  // ---- write agg into s_a overlay: s_agg[i][512] f32 (8 KB) ----
  float* s_agg = (float*)s_a;
  if (g == 0) {
    #pragma unroll
    for (int p = 0; p < 2; ++p) {
      const int h = 2 * w + p;
      #pragma unroll
      for (int mt = 0; mt < G_; ++mt)
        #pragma unroll
        for (int tt = 0; tt < 4; ++tt)
          s_agg[mt * DH + h * 64 + tt * 16 + c16] = agg[p][mt][tt];
    }
  }
  __syncthreads();

  // ---- out = agg @ Wout; wave w sums k-range [w*128, w*128+128) ----
  float* s_part = (float*)s_a + G_ * DH;   // bytes [8KB, 24KB)
  f32x4 oacc[G_];
  #pragma unroll
  for (int i = 0; i < G_; ++i) oacc[i] = zero4;
  for (int c4 = 0; c4 < 32; ++c4) {
    const int c = w * 128 + c4 * 4;
    f32x4 ag[G_];
    #pragma unroll
    for (int i = 0; i < G_; ++i) ag[i] = *(const f32x4*)&s_agg[i * DH + c];
    #pragma unroll
    for (int cc = 0; cc < 4; ++cc) {
      const f32x4 wv = *(const f32x4*)&Wout[(size_t)(c + cc) * DM + lane * 4];
      #pragma unroll
      for (int i = 0; i < G_; ++i) oacc[i] += wv * ag[i][cc];
    }
  }
  #pragma unroll
  for (int i = 0; i < G_; ++i)
    *(f32x4*)&s_part[(w * G_ + i) * DM + lane * 4] = oacc[i];
  __syncthreads();

  #pragma unroll
  for (int i = 0; i < G_; ++i) {
    const float o = s_part[(0 * G_ + i) * DM + t] + s_part[(1 * G_ + i) * DM + t]
                  + s_part[(2 * G_ + i) * DM + t] + s_part[(3 * G_ + i) * DM + t];
    out[(size_t)(bi0 + i) * DM + t] = o;
  }
}

// ---------------------------------------------------------------------------
extern "C" void kernel_launch(void* const* d_in, const int* in_sizes, int n_in,
                              void* d_out, int out_size, void* d_ws, size_t ws_size,
                              hipStream_t stream)
{
  const float* q    = (const float*)d_in[0];
  const float* k    = (const float*)d_in[1];
  const float* pos  = (const float*)d_in[2];
  const int*   lidx = (const int*)d_in[3];
  const float* Wq   = (const float*)d_in[4];
  const float* Wkv  = (const float*)d_in[5];
  const float* W1   = (const float*)d_in[6];
  const float* b1   = (const float*)d_in[7];
  const float* W2   = (const float*)d_in[8];
  const float* b2   = (const float*)d_in[9];
  const float* Wout = (const float*)d_in[10];
  float* out = (float*)d_out;

  // ws: qh 8MB | kv 16MB | W1f 512KB | W2f 1MB
  float* qh_ws = (float*)d_ws;
  float* kv_ws = qh_ws + (size_t)(B_ * I_) * DH;
  unsigned short* W1f = (unsigned short*)(kv_ws + (size_t)(B_ * NK_) * (2 * DH));
  unsigned short* W2f = W1f + (size_t)DH * DH;

  pre_kernel<<<1408, 256, 0, stream>>>(q, k, Wq, Wkv, W1, W2,
                                       qh_ws, kv_ws, W1f, W2f);
  fused_mfma<<<(B_ * I_) / G_, 256, 0, stream>>>(pos, lidx, qh_ws, kv_ws,
                                                 W1f, b1, W2f, b2, Wout, out);
}